// Round 1
// baseline (1064.864 us; speedup 1.0000x reference)
//
#include <hip/hip_runtime.h>

// SSD scan: y[b,t,h,p] = sum_n h_t[b,h,p,n] * C[b,t,n]
//           h_t = exp(-exp(A_log[h]) * delta[b,t,h]) * h_{t-1}
//                 + delta[b,t,h] * X[b,t,h,p] * B[b,t,n]
// Layout: one wave (64 lanes) per (b,h,p); lane index = n.
// 2048 blocks x 64 threads. B/C row loads are coalesced across lanes;
// delta/X are wave-uniform (scalar loads). y needs a 64-lane reduction
// per timestep (6-step shfl_xor butterfly).

constexpr int BSZ = 2, T = 2048, H = 16, P = 64, N = 64;

__global__ __launch_bounds__(64) void ssd_scan_kernel(
    const float* __restrict__ X,      // [B,T,H,P]
    const float* __restrict__ delta,  // [B,T,H]
    const float* __restrict__ Bm,     // [B,T,N]
    const float* __restrict__ Cm,     // [B,T,N]
    const float* __restrict__ A_log,  // [H]
    float* __restrict__ Y,            // [B,T,H,P]
    float* __restrict__ Hlast)        // [B,H,P,N]
{
    const int lane = threadIdx.x;          // n
    const int blk  = blockIdx.x;           // b*H*P + h*P + p
    const int p = blk % P;
    const int h = (blk / P) % H;
    const int b = blk / (P * H);

    const float negA = -__expf(A_log[h]);  // wave-uniform

    const float* Bp = Bm    + (size_t)b * T * N + lane;
    const float* Cp = Cm    + (size_t)b * T * N + lane;
    const float* dp = delta + (size_t)b * T * H + h;
    const float* Xp = X     + ((size_t)b * T * H + h) * P + p;
    float*       Yp = Y     + ((size_t)b * T * H + h) * P + p;

    float hstate = 0.0f;

    #pragma unroll 4
    for (int t = 0; t < T; ++t) {
        const float bv = Bp[(size_t)t * N];        // coalesced across lanes
        const float cv = Cp[(size_t)t * N];        // coalesced across lanes
        const float dl = dp[(size_t)t * H];        // uniform
        const float xv = Xp[(size_t)t * H * P];    // uniform

        const float dA = __expf(negA * dl);
        hstate = dA * hstate + (dl * xv) * bv;

        float yv = hstate * cv;
        // 64-lane butterfly reduction
        #pragma unroll
        for (int m = 32; m >= 1; m >>= 1)
            yv += __shfl_xor(yv, m, 64);

        if (lane == 0)
            Yp[(size_t)t * H * P] = yv;
    }

    // final state: [B,H,P,N]
    Hlast[(((size_t)b * H + h) * P + p) * N + lane] = hstate;
}

extern "C" void kernel_launch(void* const* d_in, const int* in_sizes, int n_in,
                              void* d_out, int out_size, void* d_ws, size_t ws_size,
                              hipStream_t stream) {
    const float* X     = (const float*)d_in[0];
    const float* delta = (const float*)d_in[1];
    const float* Bm    = (const float*)d_in[2];
    const float* Cm    = (const float*)d_in[3];
    const float* A_log = (const float*)d_in[4];

    float* Y     = (float*)d_out;
    float* Hlast = (float*)d_out + (size_t)BSZ * T * H * P;

    dim3 grid(BSZ * H * P);
    dim3 block(64);
    ssd_scan_kernel<<<grid, block, 0, stream>>>(X, delta, Bm, Cm, A_log, Y, Hlast);
}

// Round 2
// 163.739 us; speedup vs baseline: 6.5034x; 6.5034x over previous
//
#include <hip/hip_runtime.h>

// Chunked linear-scan decomposition of the SSD layer.
//   h_t = dA_t * h_{t-1} + delta_t * X_t[p] * B_t[n];  y_t[p] = sum_n h_t[p,n] C_t[n]
// K1: per-chunk local scan (h0=0) -> Hend + chunk decay D
// K2: 32-chunk scan per (b,h,p,n) element -> Hstart (in-place) + final state out
// K3: per-chunk replay from Hstart -> y
// Mapping in K1/K3: lane = p, 64 n-states in registers; B/C rows broadcast from LDS
// (float4, same-address = conflict-free); X/delta staged in LDS. Block = 4 waves =
// 4 adjacent h sharing B/C staging. Grid = 256 blocks = 1 block/CU.

constexpr int BSZ = 2, T = 2048, H = 16, P = 64, N = 64;
constexpr int L  = 64;          // chunk length
constexpr int NC = T / L;       // 32 chunks
constexpr int HB = 4;           // h per block
constexpr int NHB = H / HB;     // 4 h-groups

// ---------------- Kernel 1: chunk-local end states ----------------
__global__ __launch_bounds__(256) void k1_chunk_end(
    const float* __restrict__ X,      // [B,T,H,P]
    const float* __restrict__ delta,  // [B,T,H]
    const float* __restrict__ Bm,     // [B,T,N]
    const float* __restrict__ A_log,  // [H]
    float* __restrict__ Hbuf,         // [B*H*NC, P, N]  (chunk-local end states)
    float* __restrict__ Dchunk)       // [B*H*NC]
{
    __shared__ float sB[L * N];        // [t][n]   16 KB
    __shared__ float sX[L * HB * P];   // [t][h'][p] 64 KB
    __shared__ float sDl[L * HB];      // [t][h']   1 KB

    const int tid  = threadIdx.x;
    const int lane = tid & 63;         // p
    const int w    = tid >> 6;         // h' within block
    const int blk  = blockIdx.x;       // ((b*NC)+c)*NHB + hg
    const int hg   = blk & (NHB - 1);
    const int c    = (blk >> 2) & (NC - 1);
    const int b    = blk >> 7;
    const int h0   = hg * HB;
    const int t0   = c * L;

    // stage B chunk: 1024 float4
    {
        const float4* gB4 = (const float4*)(Bm + ((size_t)b * T + t0) * N);
        float4* sB4 = (float4*)sB;
        #pragma unroll
        for (int r = 0; r < 4; ++r) sB4[r * 256 + tid] = gB4[r * 256 + tid];
    }
    // stage X slab [t][h0..h0+3][p]: per t, 64 float4 contiguous
    {
        const float4* gX4 = (const float4*)(X + (((size_t)b * T + t0) * H + h0) * P);
        float4* sX4 = (float4*)sX;
        const int tq = tid >> 6, q = tid & 63;
        #pragma unroll
        for (int r = 0; r < 16; ++r) {
            int t = r * 4 + tq;
            sX4[t * 64 + q] = gX4[(size_t)t * (H * P / 4) + q];
        }
    }
    // stage delta [t][h']
    {
        const int t = tid >> 2, hh = tid & 3;
        sDl[t * HB + hh] = delta[((size_t)b * T + t0 + t) * H + h0 + hh];
    }
    __syncthreads();

    const int h = h0 + w;
    const float negA = -__expf(A_log[h]);
    const float* myX = sX + w * P;

    float hn[64];
    #pragma unroll
    for (int n = 0; n < 64; ++n) hn[n] = 0.0f;
    float sumdl = 0.0f;

    for (int t = 0; t < L; ++t) {
        const float dl = sDl[t * HB + w];
        const float xv = myX[t * (HB * P) + lane];
        const float dA = __expf(negA * dl);
        const float k  = dl * xv;
        sumdl += dl;
        const float4* row = (const float4*)(sB + t * N);
        #pragma unroll
        for (int q = 0; q < 16; ++q) {
            float4 bq = row[q];
            hn[4*q+0] = dA * hn[4*q+0] + k * bq.x;
            hn[4*q+1] = dA * hn[4*q+1] + k * bq.y;
            hn[4*q+2] = dA * hn[4*q+2] + k * bq.z;
            hn[4*q+3] = dA * hn[4*q+3] + k * bq.w;
        }
    }

    const int bh = b * H + h;
    const int chunkid = bh * NC + c;
    float4* o4 = (float4*)(Hbuf + ((size_t)chunkid * P + lane) * N);
    #pragma unroll
    for (int q = 0; q < 16; ++q)
        o4[q] = make_float4(hn[4*q+0], hn[4*q+1], hn[4*q+2], hn[4*q+3]);
    if (lane == 0) Dchunk[chunkid] = __expf(negA * sumdl);
}

// ---------------- Kernel 2: scan over chunks ----------------
__global__ __launch_bounds__(256) void k2_scan(
    const float* __restrict__ Dchunk,
    float* __restrict__ Hbuf,          // in: Hend, out: Hstart (in-place)
    float* __restrict__ Hlast)         // [B,H,P,N] final state (d_out tail)
{
    const int idx = blockIdx.x * 256 + threadIdx.x;  // over B*H*P*N = 131072
    const int bh  = idx >> 12;                       // (b*H+h)
    const int rem = idx & 4095;                      // p*64+n
    float hs = 0.0f;
    #pragma unroll 4
    for (int c = 0; c < NC; ++c) {
        const size_t off = ((size_t)(bh * NC + c) << 12) + rem;
        const float tmp = Hbuf[off];
        const float D   = Dchunk[bh * NC + c];
        Hbuf[off] = hs;                 // Hstart for chunk c
        hs = D * hs + tmp;
    }
    Hlast[idx] = hs;
}

// ---------------- Kernel 3: replay with y ----------------
__global__ __launch_bounds__(256) void k3_y(
    const float* __restrict__ X,
    const float* __restrict__ delta,
    const float* __restrict__ Bm,
    const float* __restrict__ Cm,
    const float* __restrict__ A_log,
    const float* __restrict__ Hbuf,    // Hstart
    float* __restrict__ Y)             // [B,T,H,P]
{
    __shared__ float sB[L * N];        // 16 KB
    __shared__ float sC[L * N];        // 16 KB
    __shared__ float sX[L * HB * P];   // 64 KB
    __shared__ float sDl[L * HB];      // 1 KB

    const int tid  = threadIdx.x;
    const int lane = tid & 63;         // p
    const int w    = tid >> 6;
    const int blk  = blockIdx.x;
    const int hg   = blk & (NHB - 1);
    const int c    = (blk >> 2) & (NC - 1);
    const int b    = blk >> 7;
    const int h0   = hg * HB;
    const int t0   = c * L;

    {
        const float4* gB4 = (const float4*)(Bm + ((size_t)b * T + t0) * N);
        const float4* gC4 = (const float4*)(Cm + ((size_t)b * T + t0) * N);
        float4* sB4 = (float4*)sB;
        float4* sC4 = (float4*)sC;
        #pragma unroll
        for (int r = 0; r < 4; ++r) {
            sB4[r * 256 + tid] = gB4[r * 256 + tid];
            sC4[r * 256 + tid] = gC4[r * 256 + tid];
        }
    }
    {
        const float4* gX4 = (const float4*)(X + (((size_t)b * T + t0) * H + h0) * P);
        float4* sX4 = (float4*)sX;
        const int tq = tid >> 6, q = tid & 63;
        #pragma unroll
        for (int r = 0; r < 16; ++r) {
            int t = r * 4 + tq;
            sX4[t * 64 + q] = gX4[(size_t)t * (H * P / 4) + q];
        }
    }
    {
        const int t = tid >> 2, hh = tid & 3;
        sDl[t * HB + hh] = delta[((size_t)b * T + t0 + t) * H + h0 + hh];
    }
    __syncthreads();

    const int h = h0 + w;
    const float negA = -__expf(A_log[h]);
    const float* myX = sX + w * P;
    const int bh = b * H + h;
    const int chunkid = bh * NC + c;

    float hn[64];
    {
        const float4* hin = (const float4*)(Hbuf + ((size_t)chunkid * P + lane) * N);
        #pragma unroll
        for (int q = 0; q < 16; ++q) {
            float4 v = hin[q];
            hn[4*q+0] = v.x; hn[4*q+1] = v.y; hn[4*q+2] = v.z; hn[4*q+3] = v.w;
        }
    }

    float* yb = Y + (((size_t)b * T + t0) * H + h) * P + lane;

    for (int t = 0; t < L; ++t) {
        const float dl = sDl[t * HB + w];
        const float xv = myX[t * (HB * P) + lane];
        const float dA = __expf(negA * dl);
        const float k  = dl * xv;
        const float4* rowB = (const float4*)(sB + t * N);
        const float4* rowC = (const float4*)(sC + t * N);
        float y0 = 0.f, y1 = 0.f, y2 = 0.f, y3 = 0.f;
        #pragma unroll
        for (int q = 0; q < 16; ++q) {
            float4 bq = rowB[q];
            float4 cq = rowC[q];
            hn[4*q+0] = dA * hn[4*q+0] + k * bq.x;  y0 += hn[4*q+0] * cq.x;
            hn[4*q+1] = dA * hn[4*q+1] + k * bq.y;  y1 += hn[4*q+1] * cq.y;
            hn[4*q+2] = dA * hn[4*q+2] + k * bq.z;  y2 += hn[4*q+2] * cq.z;
            hn[4*q+3] = dA * hn[4*q+3] + k * bq.w;  y3 += hn[4*q+3] * cq.w;
        }
        yb[(size_t)t * (H * P)] = (y0 + y1) + (y2 + y3);
    }
}

extern "C" void kernel_launch(void* const* d_in, const int* in_sizes, int n_in,
                              void* d_out, int out_size, void* d_ws, size_t ws_size,
                              hipStream_t stream) {
    const float* X     = (const float*)d_in[0];
    const float* delta = (const float*)d_in[1];
    const float* Bm    = (const float*)d_in[2];
    const float* Cm    = (const float*)d_in[3];
    const float* A_log = (const float*)d_in[4];

    float* Y     = (float*)d_out;
    float* Hlast = (float*)d_out + (size_t)BSZ * T * H * P;

    float* Hbuf   = (float*)d_ws;                                  // 1024*4096 floats
    float* Dchunk = (float*)d_ws + (size_t)BSZ * H * NC * P * N;   // +1024 floats

    const int nblk = BSZ * NC * NHB;   // 256
    k1_chunk_end<<<nblk, 256, 0, stream>>>(X, delta, Bm, A_log, Hbuf, Dchunk);
    k2_scan<<<(BSZ * H * P * N) / 256, 256, 0, stream>>>(Dchunk, Hbuf, Hlast);
    k3_y<<<nblk, 256, 0, stream>>>(X, delta, Bm, Cm, A_log, Hbuf, Y);
}

// Round 3
// 107.604 us; speedup vs baseline: 9.8962x; 1.5217x over previous
//
#include <hip/hip_runtime.h>

// Mamba-2 style chunked quadratic formulation on MFMA (bf16 in, fp32 acc).
// Per (b,h,c) chunk of L=64 steps, one wave does:
//   s_t   = inclusive cumsum of negA*delta            (wave shfl scan)
//   G     = C . B^T                (64x64x64 MFMA GEMM, K=n)
//   S     = mask(tau<=t) exp(s_t - s_tau + ln d_tau) * G   (elementwise, D-layout)
//   Yint  = S . X                  (K=tau; S via LDS round-trip D->A layout)
//   Hend0 = (w . X)^T . B          (w_tau = exp(s_L - s_tau) d_tau; K=tau)
// P2: 32-chunk serial scan over Hend0 -> Hstart (in place) + Hlast.
// P3: Y += exp(s_t) * C . Hstart   (one GEMM per chunk; Lambda recomputed).
// MFMA 16x16x32 bf16 layouts (HW-verified per guide):
//   A: m=lane&15, k=quad*8+j    B: n=lane&15, k=quad*8+j
//   D: n(col)=lane&15, m(row)=quad*4+reg
// LDS rows padded to 72 bf16 (144 B = 36 words) -> b128 frag reads hit all 32
// banks evenly (volume-optimal); 16 B row alignment preserved.

constexpr int BSZ = 2, T = 2048, H = 16, P = 64, N = 64;
constexpr int L = 64, NC = T / L;     // 32 chunks
constexpr int HB = 4, NHB = H / HB;   // 4 h per block, 4 h-groups
constexpr int LS = 72;                // LDS row stride in ushorts

using bf16x8 = __attribute__((ext_vector_type(8))) short;
using f32x4  = __attribute__((ext_vector_type(4))) float;

__device__ inline ushort f2bf(float f) {
    unsigned u = __float_as_uint(f);
    u += 0x7FFFu + ((u >> 16) & 1u);   // RTN-even
    return (ushort)(u >> 16);
}
__device__ inline unsigned pack2(float a, float b) {
    return (unsigned)f2bf(a) | ((unsigned)f2bf(b) << 16);
}
__device__ inline float bf2f(ushort h) {
    return __uint_as_float(((unsigned)h) << 16);
}

// ---------------- P1: intra-chunk (Y_intra, Hend0, Dchunk) ----------------
__global__ __launch_bounds__(256, 1) void p1_intra(
    const float* __restrict__ X, const float* __restrict__ delta,
    const float* __restrict__ Bm, const float* __restrict__ Cm,
    const float* __restrict__ A_log,
    float* __restrict__ Y, float* __restrict__ Hbuf, float* __restrict__ Dchunk)
{
    __shared__ __align__(16) ushort sB [64 * LS];      // [tau][n]
    __shared__ __align__(16) ushort sC [64 * LS];      // [t][n]
    __shared__ __align__(16) ushort sBt[64 * LS];      // [n][tau]
    __shared__ __align__(16) ushort sXt[HB][64 * LS];  // [p][tau] per wave/h
    __shared__ __align__(16) ushort sS [HB][64 * LS];  // [t][tau] per wave/h
    __shared__ float sSa[HB][64], sSb[HB][64], sW[HB][64];

    const int tid  = threadIdx.x, lane = tid & 63, w = tid >> 6;
    const int quad = lane >> 4,   l16  = lane & 15;
    const int blk = blockIdx.x;
    const int hg  = blk & (NHB - 1);
    const int c   = (blk >> 2) & (NC - 1);
    const int b   = blk >> 7;
    const int h   = hg * HB + w;
    const int t0  = c * L;
    const int chunkid = (b * H + h) * NC + c;

    // stage B,C -> bf16 [t][n]
    {
        const float4* gB4 = (const float4*)(Bm + ((size_t)b * T + t0) * N);
        const float4* gC4 = (const float4*)(Cm + ((size_t)b * T + t0) * N);
        #pragma unroll
        for (int r = 0; r < 4; ++r) {
            int idx = r * 256 + tid;
            int t = idx >> 4, n4 = (idx & 15) << 2;
            float4 vb = gB4[idx], vc = gC4[idx];
            *(uint2*)&sB[t * LS + n4] = make_uint2(pack2(vb.x, vb.y), pack2(vb.z, vb.w));
            *(uint2*)&sC[t * LS + n4] = make_uint2(pack2(vc.x, vc.y), pack2(vc.z, vc.w));
        }
    }
    // transpose B -> sBt [n][tau] (waves split tau range)
    {
        const float* gB = Bm + ((size_t)b * T + t0) * N;
        #pragma unroll
        for (int i = 0; i < 8; ++i) {
            int tau = (w * 8 + i) * 2;
            float v0 = gB[(size_t)tau * N + lane];
            float v1 = gB[(size_t)(tau + 1) * N + lane];
            *(unsigned*)&sBt[lane * LS + tau] = pack2(v0, v1);
        }
    }
    // transpose X -> sXt[w] [p][tau]
    {
        const float* gX = X + (((size_t)b * T + t0) * H + h) * P;
        #pragma unroll 8
        for (int i = 0; i < 32; ++i) {
            float v0 = gX[(size_t)(2 * i)     * (H * P) + lane];
            float v1 = gX[(size_t)(2 * i + 1) * (H * P) + lane];
            *(unsigned*)&sXt[w][lane * LS + 2 * i] = pack2(v0, v1);
        }
    }
    // delta scan: s_t (inclusive), sb[tau] = ln d - s, w[tau] = exp(sL - s + ln d)
    const float negA = -__expf(A_log[h]);
    {
        float dl = delta[((size_t)b * T + t0 + lane) * H + h];
        float s = negA * dl;
        #pragma unroll
        for (int off = 1; off < 64; off <<= 1) {
            float u = __shfl_up(s, off, 64);
            if (lane >= off) s += u;
        }
        float sL  = __shfl(s, 63, 64);
        float lnd = __logf(dl);
        sSa[w][lane] = s;
        sSb[w][lane] = lnd - s;
        sW [w][lane] = __expf(sL + lnd - s);
        if (lane == 63) Dchunk[chunkid] = __expf(sL);
    }
    __syncthreads();

    // G = C . B^T   (D: m=t, n=tau)
    f32x4 g[4][4];
    #pragma unroll
    for (int i = 0; i < 4; ++i)
        #pragma unroll
        for (int j = 0; j < 4; ++j) g[i][j] = (f32x4){0.f, 0.f, 0.f, 0.f};
    #pragma unroll
    for (int ks = 0; ks < 2; ++ks) {
        const int ko = ks * 32 + quad * 8;
        bf16x8 af[4], bfr[4];
        #pragma unroll
        for (int i = 0; i < 4; ++i) af[i]  = *(const bf16x8*)&sC[(i * 16 + l16) * LS + ko];
        #pragma unroll
        for (int j = 0; j < 4; ++j) bfr[j] = *(const bf16x8*)&sB[(j * 16 + l16) * LS + ko];
        #pragma unroll
        for (int i = 0; i < 4; ++i)
            #pragma unroll
            for (int j = 0; j < 4; ++j)
                g[i][j] = __builtin_amdgcn_mfma_f32_16x16x32_bf16(af[i], bfr[j], g[i][j], 0, 0, 0);
    }

    // S = mask * exp(sa[t] + sb[tau]) * G  -> bf16 LDS [t][tau]
    #pragma unroll
    for (int jt = 0; jt < 4; ++jt) {
        const int tau = jt * 16 + l16;
        const float sb = sSb[w][tau];
        #pragma unroll
        for (int it = 0; it < 4; ++it) {
            #pragma unroll
            for (int r = 0; r < 4; ++r) {
                const int t = it * 16 + quad * 4 + r;
                float arg = (tau <= t) ? (sSa[w][t] + sb) : -80.0f;
                float sv = __expf(arg) * g[it][jt][r];
                sS[w][t * LS + tau] = f2bf(sv);
            }
        }
    }
    __syncthreads();

    // Y_intra = S . X  (K=tau)   and   Hend0 = (w*X)^T . B  (K=tau)
    f32x4 ya[4][4], ha[4][4];
    #pragma unroll
    for (int i = 0; i < 4; ++i)
        #pragma unroll
        for (int j = 0; j < 4; ++j) {
            ya[i][j] = (f32x4){0.f, 0.f, 0.f, 0.f};
            ha[i][j] = (f32x4){0.f, 0.f, 0.f, 0.f};
        }
    #pragma unroll
    for (int ks = 0; ks < 2; ++ks) {
        const int ko = ks * 32 + quad * 8;
        bf16x8 sa[4], xb[4], bb[4], xw[4];
        #pragma unroll
        for (int i = 0; i < 4; ++i) sa[i] = *(const bf16x8*)&sS [w][(i * 16 + l16) * LS + ko];
        #pragma unroll
        for (int i = 0; i < 4; ++i) xb[i] = *(const bf16x8*)&sXt[w][(i * 16 + l16) * LS + ko];
        #pragma unroll
        for (int i = 0; i < 4; ++i) bb[i] = *(const bf16x8*)&sBt[(i * 16 + l16) * LS + ko];
        float wv[8];
        #pragma unroll
        for (int j = 0; j < 8; ++j) wv[j] = sW[w][ko + j];
        #pragma unroll
        for (int i = 0; i < 4; ++i)
            #pragma unroll
            for (int j = 0; j < 8; ++j)
                xw[i][j] = (short)f2bf(bf2f((ushort)xb[i][j]) * wv[j]);
        #pragma unroll
        for (int it = 0; it < 4; ++it)
            #pragma unroll
            for (int jt = 0; jt < 4; ++jt)
                ya[it][jt] = __builtin_amdgcn_mfma_f32_16x16x32_bf16(sa[it], xb[jt], ya[it][jt], 0, 0, 0);
        #pragma unroll
        for (int ip = 0; ip < 4; ++ip)
            #pragma unroll
            for (int jn = 0; jn < 4; ++jn)
                ha[ip][jn] = __builtin_amdgcn_mfma_f32_16x16x32_bf16(xw[ip], bb[jn], ha[ip][jn], 0, 0, 0);
    }

    // stores: Y_intra (D-layout scatter) and Hend0 [p][n]
    float* Yg = Y + (((size_t)b * T + t0) * H + h) * P;
    #pragma unroll
    for (int it = 0; it < 4; ++it)
        #pragma unroll
        for (int jt = 0; jt < 4; ++jt)
            #pragma unroll
            for (int r = 0; r < 4; ++r)
                Yg[(size_t)(it * 16 + quad * 4 + r) * (H * P) + jt * 16 + l16] = ya[it][jt][r];
    float* Hg = Hbuf + (size_t)chunkid * (P * N);
    #pragma unroll
    for (int ip = 0; ip < 4; ++ip)
        #pragma unroll
        for (int jn = 0; jn < 4; ++jn)
            #pragma unroll
            for (int r = 0; r < 4; ++r)
                Hg[(ip * 16 + quad * 4 + r) * N + jn * 16 + l16] = ha[ip][jn][r];
}

// ---------------- P2: serial scan over chunks ----------------
__global__ __launch_bounds__(256) void p2_scan(
    const float* __restrict__ Dchunk, float* __restrict__ Hbuf,
    float* __restrict__ Hlast)
{
    const int idx = blockIdx.x * 256 + threadIdx.x;   // 32768 float4 lanes
    const int bh = idx >> 10, e4 = idx & 1023;
    float4* H4 = (float4*)Hbuf;
    float4 hs = {0.f, 0.f, 0.f, 0.f};
    #pragma unroll 4
    for (int c = 0; c < NC; ++c) {
        const size_t off = ((size_t)(bh * NC + c) << 10) + e4;
        float4 tmp = H4[off];
        float D = Dchunk[bh * NC + c];
        H4[off] = hs;                      // Hstart for chunk c
        hs.x = D * hs.x + tmp.x;
        hs.y = D * hs.y + tmp.y;
        hs.z = D * hs.z + tmp.z;
        hs.w = D * hs.w + tmp.w;
    }
    ((float4*)Hlast)[idx] = hs;
}

// ---------------- P3: Y += Lambda_t * C . Hstart ----------------
__global__ __launch_bounds__(256, 1) void p3_inter(
    const float* __restrict__ delta, const float* __restrict__ Cm,
    const float* __restrict__ A_log, const float* __restrict__ Hbuf,
    float* __restrict__ Y)
{
    __shared__ __align__(16) ushort sC[64 * LS];       // [t][n]
    __shared__ __align__(16) ushort sH[HB][64 * LS];   // [p][n] per wave/h
    __shared__ float sLam[HB][64];

    const int tid  = threadIdx.x, lane = tid & 63, w = tid >> 6;
    const int quad = lane >> 4,   l16  = lane & 15;
    const int blk = blockIdx.x;
    const int hg  = blk & (NHB - 1);
    const int c   = (blk >> 2) & (NC - 1);
    const int b   = blk >> 7;
    const int h   = hg * HB + w;
    const int t0  = c * L;
    const int chunkid = (b * H + h) * NC + c;

    {
        const float4* gC4 = (const float4*)(Cm + ((size_t)b * T + t0) * N);
        #pragma unroll
        for (int r = 0; r < 4; ++r) {
            int idx = r * 256 + tid;
            int t = idx >> 4, n4 = (idx & 15) << 2;
            float4 vc = gC4[idx];
            *(uint2*)&sC[t * LS + n4] = make_uint2(pack2(vc.x, vc.y), pack2(vc.z, vc.w));
        }
    }
    {
        float dl = delta[((size_t)b * T + t0 + lane) * H + h];
        float s = -__expf(A_log[h]) * dl;
        #pragma unroll
        for (int off = 1; off < 64; off <<= 1) {
            float u = __shfl_up(s, off, 64);
            if (lane >= off) s += u;
        }
        sLam[w][lane] = __expf(s);
    }
    {
        const float4* Hg4 = (const float4*)(Hbuf + (size_t)chunkid * (P * N));
        #pragma unroll
        for (int i = 0; i < 16; ++i) {
            int idx = i * 64 + lane;
            float4 v = Hg4[idx];
            int p = idx >> 4, n4 = (idx & 15) << 2;
            *(uint2*)&sH[w][p * LS + n4] = make_uint2(pack2(v.x, v.y), pack2(v.z, v.w));
        }
    }
    __syncthreads();

    f32x4 acc[4][4];
    #pragma unroll
    for (int i = 0; i < 4; ++i)
        #pragma unroll
        for (int j = 0; j < 4; ++j) acc[i][j] = (f32x4){0.f, 0.f, 0.f, 0.f};
    #pragma unroll
    for (int ks = 0; ks < 2; ++ks) {
        const int ko = ks * 32 + quad * 8;
        bf16x8 ca[4], hb[4];
        #pragma unroll
        for (int i = 0; i < 4; ++i) ca[i] = *(const bf16x8*)&sC[(i * 16 + l16) * LS + ko];
        #pragma unroll
        for (int j = 0; j < 4; ++j) hb[j] = *(const bf16x8*)&sH[w][(j * 16 + l16) * LS + ko];
        #pragma unroll
        for (int it = 0; it < 4; ++it)
            #pragma unroll
            for (int jp = 0; jp < 4; ++jp)
                acc[it][jp] = __builtin_amdgcn_mfma_f32_16x16x32_bf16(ca[it], hb[jp], acc[it][jp], 0, 0, 0);
    }

    float* Yg = Y + (((size_t)b * T + t0) * H + h) * P;
    #pragma unroll
    for (int it = 0; it < 4; ++it)
        #pragma unroll
        for (int jp = 0; jp < 4; ++jp)
            #pragma unroll
            for (int r = 0; r < 4; ++r) {
                const int t = it * 16 + quad * 4 + r;
                const size_t off = (size_t)t * (H * P) + jp * 16 + l16;
                Yg[off] = Yg[off] + sLam[w][t] * acc[it][jp][r];
            }
}

extern "C" void kernel_launch(void* const* d_in, const int* in_sizes, int n_in,
                              void* d_out, int out_size, void* d_ws, size_t ws_size,
                              hipStream_t stream) {
    const float* X     = (const float*)d_in[0];
    const float* delta = (const float*)d_in[1];
    const float* Bm    = (const float*)d_in[2];
    const float* Cm    = (const float*)d_in[3];
    const float* A_log = (const float*)d_in[4];

    float* Y     = (float*)d_out;
    float* Hlast = (float*)d_out + (size_t)BSZ * T * H * P;

    float* Hbuf   = (float*)d_ws;
    float* Dchunk = (float*)d_ws + (size_t)BSZ * H * NC * P * N;

    const int nblk = BSZ * NC * NHB;   // 256
    p1_intra<<<nblk, 256, 0, stream>>>(X, delta, Bm, Cm, A_log, Y, Hbuf, Dchunk);
    p2_scan<<<(BSZ * H * P * N / 4) / 256, 256, 0, stream>>>(Dchunk, Hbuf, Hlast);
    p3_inter<<<nblk, 256, 0, stream>>>(delta, Cm, A_log, Hbuf, Y);
}

// Round 4
// 103.275 us; speedup vs baseline: 10.3110x; 1.0419x over previous
//
#include <hip/hip_runtime.h>

// Mamba-2 chunked SSD on MFMA, round 4: each (b,h,c) chunk handled by one
// 4-wave block; wave w owns a 16-row strip. LDS single-copy (47 KB) -> 3
// blocks/CU (3 waves/SIMD) for P1; P2 batches all 32 chunk loads into regs.
//   P1: G=C.B^T -> S=mask*exp(.)*G -> Yint=S.X, Hend0=(w*X)^T.B
//   P2: 32-chunk scan -> Hstart (in place) + Hlast
//   P3: Y += Lambda_t * C . Hstart
// MFMA 16x16x32 bf16: A m=lane&15,k=quad*8+j; B n=lane&15,k=quad*8+j;
//                     D col=lane&15, row=quad*4+reg.
// LDS rows padded to 72 bf16 (36 words) so b128 frag reads spread banks.

constexpr int BSZ = 2, T = 2048, H = 16, P = 64, N = 64;
constexpr int L = 64, NC = T / L;   // 32 chunks
constexpr int LS = 72;              // LDS row stride (ushorts)

using bf16x8 = __attribute__((ext_vector_type(8))) short;
using f32x4  = __attribute__((ext_vector_type(4))) float;

__device__ inline ushort f2bf(float f) {
    unsigned u = __float_as_uint(f);
    u += 0x7FFFu + ((u >> 16) & 1u);
    return (ushort)(u >> 16);
}
__device__ inline unsigned pack2(float a, float b) {
    return (unsigned)f2bf(a) | ((unsigned)f2bf(b) << 16);
}
__device__ inline float bf2f(ushort h) {
    return __uint_as_float(((unsigned)h) << 16);
}

// ---------------- P1: intra-chunk ----------------
__global__ __launch_bounds__(256, 3) void p1_intra(
    const float* __restrict__ X, const float* __restrict__ delta,
    const float* __restrict__ Bm, const float* __restrict__ Cm,
    const float* __restrict__ A_log,
    float* __restrict__ Y, float* __restrict__ Hbuf, float* __restrict__ Dchunk)
{
    __shared__ __align__(16) ushort sB [64 * LS];   // [tau][n]
    __shared__ __align__(16) ushort sC [64 * LS];   // [t][n]
    __shared__ __align__(16) ushort sBt[64 * LS];   // [n][tau]
    __shared__ __align__(16) ushort sXt[64 * LS];   // [p][tau]
    __shared__ __align__(16) ushort sS [64 * LS];   // [t][tau]
    __shared__ float sSa[64], sSb[64], sW[64];

    const int tid  = threadIdx.x, lane = tid & 63, w = tid >> 6;
    const int quad = lane >> 4,   l16  = lane & 15;
    const int blk = blockIdx.x;               // ((b*NC)+c)*H + h  (h fastest)
    const int h   = blk & (H - 1);
    const int c   = (blk >> 4) & (NC - 1);
    const int b   = blk >> 9;
    const int t0  = c * L;
    const int chunkid = (b * H + h) * NC + c;

    // stage B,C -> bf16 [t][n]
    {
        const float4* gB4 = (const float4*)(Bm + ((size_t)b * T + t0) * N);
        const float4* gC4 = (const float4*)(Cm + ((size_t)b * T + t0) * N);
        #pragma unroll
        for (int r = 0; r < 4; ++r) {
            int idx = r * 256 + tid, t = idx >> 4, n4 = (idx & 15) << 2;
            float4 vb = gB4[idx], vc = gC4[idx];
            *(uint2*)&sB[t * LS + n4] = make_uint2(pack2(vb.x, vb.y), pack2(vb.z, vb.w));
            *(uint2*)&sC[t * LS + n4] = make_uint2(pack2(vc.x, vc.y), pack2(vc.z, vc.w));
        }
    }
    // transpose B -> [n][tau]
    {
        const float* gB = Bm + ((size_t)b * T + t0) * N;
        #pragma unroll
        for (int i = 0; i < 8; ++i) {
            int tau = (w * 8 + i) * 2;
            float v0 = gB[(size_t)tau * N + lane];
            float v1 = gB[(size_t)(tau + 1) * N + lane];
            *(unsigned*)&sBt[lane * LS + tau] = pack2(v0, v1);
        }
    }
    // transpose X (this h) -> [p][tau]; wave w covers tau in [16w,16w+16)
    {
        const float* gX = X + (((size_t)b * T + t0) * H + h) * P;
        #pragma unroll
        for (int i = 0; i < 8; ++i) {
            int tau = w * 16 + 2 * i;
            float v0 = gX[(size_t)tau * (H * P) + lane];
            float v1 = gX[(size_t)(tau + 1) * (H * P) + lane];
            *(unsigned*)&sXt[lane * LS + tau] = pack2(v0, v1);
        }
    }
    // delta cumsum (wave 0)
    if (w == 0) {
        float dl = delta[((size_t)b * T + t0 + lane) * H + h];
        float s = -__expf(A_log[h]) * dl;
        #pragma unroll
        for (int off = 1; off < 64; off <<= 1) {
            float u = __shfl_up(s, off, 64);
            if (lane >= off) s += u;
        }
        float sL  = __shfl(s, 63, 64);
        float lnd = __logf(dl);
        sSa[lane] = s;
        sSb[lane] = lnd - s;
        sW [lane] = __expf(sL + lnd - s);
        if (lane == 63) Dchunk[chunkid] = __expf(sL);
    }
    __syncthreads();

    // G strip: rows t in [16w,16w+16), all tau
    f32x4 g[4];
    #pragma unroll
    for (int j = 0; j < 4; ++j) g[j] = (f32x4){0.f, 0.f, 0.f, 0.f};
    #pragma unroll
    for (int ks = 0; ks < 2; ++ks) {
        const int ko = ks * 32 + quad * 8;
        bf16x8 af = *(const bf16x8*)&sC[(w * 16 + l16) * LS + ko];
        #pragma unroll
        for (int jt = 0; jt < 4; ++jt) {
            bf16x8 bfr = *(const bf16x8*)&sB[(jt * 16 + l16) * LS + ko];
            g[jt] = __builtin_amdgcn_mfma_f32_16x16x32_bf16(af, bfr, g[jt], 0, 0, 0);
        }
    }
    // S strip -> bf16 LDS
    #pragma unroll
    for (int jt = 0; jt < 4; ++jt) {
        const int tau = jt * 16 + l16;
        const float sb = sSb[tau];
        #pragma unroll
        for (int r = 0; r < 4; ++r) {
            const int t = w * 16 + quad * 4 + r;
            float arg = (tau <= t) ? (sSa[t] + sb) : -80.0f;
            sS[t * LS + tau] = f2bf(__expf(arg) * g[jt][r]);
        }
    }
    __syncthreads();

    // Yint strip = S_strip . X^T   and   Hend0 strip = (w*X)^T . B
    f32x4 ya[4], ha[4];
    #pragma unroll
    for (int j = 0; j < 4; ++j) {
        ya[j] = (f32x4){0.f, 0.f, 0.f, 0.f};
        ha[j] = (f32x4){0.f, 0.f, 0.f, 0.f};
    }
    #pragma unroll
    for (int ks = 0; ks < 2; ++ks) {
        const int ko = ks * 32 + quad * 8;
        bf16x8 sa = *(const bf16x8*)&sS [(w * 16 + l16) * LS + ko];
        bf16x8 xa = *(const bf16x8*)&sXt[(w * 16 + l16) * LS + ko];
        bf16x8 xw;
        #pragma unroll
        for (int j = 0; j < 8; ++j)
            xw[j] = (short)f2bf(bf2f((ushort)xa[j]) * sW[ko + j]);
        #pragma unroll
        for (int jp = 0; jp < 4; ++jp) {
            bf16x8 xb = *(const bf16x8*)&sXt[(jp * 16 + l16) * LS + ko];
            ya[jp] = __builtin_amdgcn_mfma_f32_16x16x32_bf16(sa, xb, ya[jp], 0, 0, 0);
        }
        #pragma unroll
        for (int jn = 0; jn < 4; ++jn) {
            bf16x8 bb = *(const bf16x8*)&sBt[(jn * 16 + l16) * LS + ko];
            ha[jn] = __builtin_amdgcn_mfma_f32_16x16x32_bf16(xw, bb, ha[jn], 0, 0, 0);
        }
    }

    float* Yg = Y + (((size_t)b * T + t0) * H + h) * P;
    #pragma unroll
    for (int jp = 0; jp < 4; ++jp)
        #pragma unroll
        for (int r = 0; r < 4; ++r)
            Yg[(size_t)(w * 16 + quad * 4 + r) * (H * P) + jp * 16 + l16] = ya[jp][r];
    float* Hg = Hbuf + (size_t)chunkid * (P * N);
    #pragma unroll
    for (int jn = 0; jn < 4; ++jn)
        #pragma unroll
        for (int r = 0; r < 4; ++r)
            Hg[(w * 16 + quad * 4 + r) * N + jn * 16 + l16] = ha[jn][r];
}

// ---------------- P2: chunk scan, loads batched ----------------
__global__ __launch_bounds__(256, 4) void p2_scan(
    const float* __restrict__ Dchunk, float* __restrict__ Hbuf,
    float* __restrict__ Hlast)
{
    const int bh  = blockIdx.x >> 4;                       // uniform -> SGPR
    const int rem = ((blockIdx.x & 15) << 8) | threadIdx.x;
    float v[NC];
    #pragma unroll
    for (int c = 0; c < NC; ++c)
        v[c] = Hbuf[(((size_t)(bh * NC + c)) << 12) + rem];   // independent loads
    float hs = 0.0f;
    #pragma unroll
    for (int c = 0; c < NC; ++c) {
        const float tmp = v[c];
        v[c] = hs;                                  // Hstart for chunk c
        hs = Dchunk[bh * NC + c] * hs + tmp;
    }
    #pragma unroll
    for (int c = 0; c < NC; ++c)
        Hbuf[(((size_t)(bh * NC + c)) << 12) + rem] = v[c];
    Hlast[(size_t)bh * 4096 + rem] = hs;
}

// ---------------- P3: Y += Lambda_t * C . Hstart ----------------
__global__ __launch_bounds__(256, 4) void p3_inter(
    const float* __restrict__ delta, const float* __restrict__ Cm,
    const float* __restrict__ A_log, const float* __restrict__ Hbuf,
    float* __restrict__ Y)
{
    __shared__ __align__(16) ushort sC[64 * LS];   // [t][n]
    __shared__ __align__(16) ushort sH[64 * LS];   // [p][n]
    __shared__ float sLam[64];

    const int tid  = threadIdx.x, lane = tid & 63, w = tid >> 6;
    const int quad = lane >> 4,   l16  = lane & 15;
    const int blk = blockIdx.x;
    const int h   = blk & (H - 1);
    const int c   = (blk >> 4) & (NC - 1);
    const int b   = blk >> 9;
    const int t0  = c * L;
    const int chunkid = (b * H + h) * NC + c;

    {
        const float4* gC4 = (const float4*)(Cm + ((size_t)b * T + t0) * N);
        const float4* Hg4 = (const float4*)(Hbuf + (size_t)chunkid * (P * N));
        #pragma unroll
        for (int r = 0; r < 4; ++r) {
            int idx = r * 256 + tid, t = idx >> 4, n4 = (idx & 15) << 2;
            float4 vc = gC4[idx];
            float4 vh = Hg4[idx];
            *(uint2*)&sC[t * LS + n4] = make_uint2(pack2(vc.x, vc.y), pack2(vc.z, vc.w));
            *(uint2*)&sH[t * LS + n4] = make_uint2(pack2(vh.x, vh.y), pack2(vh.z, vh.w));
        }
    }
    if (w == 0) {
        float dl = delta[((size_t)b * T + t0 + lane) * H + h];
        float s = -__expf(A_log[h]) * dl;
        #pragma unroll
        for (int off = 1; off < 64; off <<= 1) {
            float u = __shfl_up(s, off, 64);
            if (lane >= off) s += u;
        }
        sLam[lane] = __expf(s);
    }
    __syncthreads();

    f32x4 acc[4];
    #pragma unroll
    for (int j = 0; j < 4; ++j) acc[j] = (f32x4){0.f, 0.f, 0.f, 0.f};
    #pragma unroll
    for (int ks = 0; ks < 2; ++ks) {
        const int ko = ks * 32 + quad * 8;
        bf16x8 ca = *(const bf16x8*)&sC[(w * 16 + l16) * LS + ko];
        #pragma unroll
        for (int jp = 0; jp < 4; ++jp) {
            bf16x8 hb = *(const bf16x8*)&sH[(jp * 16 + l16) * LS + ko];
            acc[jp] = __builtin_amdgcn_mfma_f32_16x16x32_bf16(ca, hb, acc[jp], 0, 0, 0);
        }
    }

    float* Yg = Y + (((size_t)b * T + t0) * H + h) * P;
    #pragma unroll
    for (int jp = 0; jp < 4; ++jp)
        #pragma unroll
        for (int r = 0; r < 4; ++r) {
            const int t = w * 16 + quad * 4 + r;
            const size_t off = (size_t)t * (H * P) + jp * 16 + l16;
            Yg[off] = Yg[off] + sLam[t] * acc[jp][r];
        }
}

extern "C" void kernel_launch(void* const* d_in, const int* in_sizes, int n_in,
                              void* d_out, int out_size, void* d_ws, size_t ws_size,
                              hipStream_t stream) {
    const float* X     = (const float*)d_in[0];
    const float* delta = (const float*)d_in[1];
    const float* Bm    = (const float*)d_in[2];
    const float* Cm    = (const float*)d_in[3];
    const float* A_log = (const float*)d_in[4];

    float* Y     = (float*)d_out;
    float* Hlast = (float*)d_out + (size_t)BSZ * T * H * P;

    float* Hbuf   = (float*)d_ws;
    float* Dchunk = (float*)d_ws + (size_t)BSZ * H * NC * P * N;

    const int nblk = BSZ * NC * H;   // 1024
    p1_intra<<<nblk, 256, 0, stream>>>(X, delta, Bm, Cm, A_log, Y, Hbuf, Dchunk);
    p2_scan<<<(BSZ * H * P * N) / 256, 256, 0, stream>>>(Dchunk, Hbuf, Hlast);
    p3_inter<<<nblk, 256, 0, stream>>>(delta, Cm, A_log, Hbuf, Y);
}